// Round 15
// baseline (85.093 us; speedup 1.0000x reference)
//
#include <hip/hip_runtime.h>

#define WDIM  256
#define NSAMP 512
#define NSIG  32
#define RB    64                 // band rows per block-task
#define NBAND 2048
#define QOFF  16                 // ints; queue table q[QOFF..]
#define WOFF  65536              // byte offset of W matrices inside d_ws

typedef float    f32x4 __attribute__((ext_vector_type(4)));
typedef _Float16 f16x8 __attribute__((ext_vector_type(8)));

__device__ __forceinline__ int reflect(int q) {
    q = (q < 0) ? (-q - 1) : q;
    return (q >= WDIM) ? (2 * WDIM - 1 - q) : q;
}

// ---- kernel 1: build 32 reflect-folded banded weight matrices (f16) ----
// W_s[i][r] = wz(r-i) + wz(-r-1-i) + wz(511-r-i), wz = masked+normalized gaussian.
__global__ __launch_bounds__(256) void build_w(const float* __restrict__ sigmas,
                                               _Float16* __restrict__ Wg) {
    __shared__ float wl[161];
    __shared__ float red;
    int s = blockIdx.x, t = threadIdx.x;
    float sigma = sigmas[s];
    float radf = floorf(4.0f * sigma + 0.5f);
    if (t < 161) {
        float off = (float)(t - 80);
        float w = 0.0f;
        if (fabsf(off) <= radf) { float z = off / sigma; w = expf(-0.5f * z * z); }
        wl[t] = w;
    }
    __syncthreads();
    if (t < 64) {
        float v = wl[t] + wl[t + 64] + (t < 33 ? wl[t + 128] : 0.0f);
        #pragma unroll
        for (int o = 32; o > 0; o >>= 1) v += __shfl_down(v, o);
        if (t == 0) red = 1.0f / v;
    }
    __syncthreads();
    float rs = red;
    int i = t;
    _Float16* wrow = Wg + ((size_t)s << 16) + (i << 8);
    for (int rq = blockIdx.y * 4; rq < blockIdx.y * 4 + 4; ++rq) {
        f16x8 v;
        #pragma unroll
        for (int j = 0; j < 8; ++j) {
            int r = rq * 8 + j;
            int d1 = r - i, d2 = -r - 1 - i, d3 = 511 - r - i;
            float w = 0.0f;
            if (d1 >= -80 && d1 <= 80) w += wl[d1 + 80];
            if (d2 >= -80)             w += wl[d2 + 80];
            if (d3 <= 80)              w += wl[d3 + 80];
            v[j] = (_Float16)(w * rs);
        }
        *(f16x8*)(wrow + rq * 8) = v;
    }
}

// ---- kernel 2: striped-LPT queue with PACKED descriptors ----
// desc = b | band<<9 | step<<11 | rad<<16  (one load decodes everything)
__global__ void build_queue(const float* __restrict__ sigmas,
                            const int* __restrict__ steps,
                            int* __restrict__ q) {
    __shared__ int hist[32];
    __shared__ int base[32];
    int t = threadIdx.x;
    if (t < 32) hist[t] = 0;
    __syncthreads();
    int nb2[2], rd2[2], st2[2];
    #pragma unroll
    for (int k = 0; k < 2; ++k) {
        int samp = t + 256 * k;
        int st = steps[samp];
        float sigma = sigmas[st];
        int rad = (int)floorf(4.0f * sigma + 0.5f);
        st2[k] = st; rd2[k] = rad;
        nb2[k] = (2 * rad + 15) >> 3;
        atomicAdd(&hist[nb2[k]], 1);
    }
    __syncthreads();
    if (t == 0) {
        int acc = 0;
        for (int bin = 31; bin >= 0; --bin) { base[bin] = acc; acc += hist[bin]; }
    }
    __syncthreads();
    #pragma unroll
    for (int k = 0; k < 2; ++k) {
        int samp = t + 256 * k;
        int r = atomicAdd(&base[nb2[k]], 1);
        int x = r & 7;
        int p = r >> 3;
        #pragma unroll
        for (int jb = 0; jb < 4; ++jb)
            q[QOFF + (((p << 2) + jb) << 3) + x] =
                samp | (jb << 9) | (st2[k] << 11) | (rd2[k] << 16);
    }
}

// ---- kernel 3: fused MFMA blur, software-pipelined. ----
// Phase V: Y = W_band X; A=W rows direct; B=X column-slices via direct dword
//          loads, PIPELINED one K-tile ahead. Y -> swizzled LDS f16.
// Phase H: Z = Y W^T; A=Y from LDS; B=W rows direct, pipelined. f32 out.
template <bool QUEUED>
__global__ __launch_bounds__(256, 2) void blur_mfma(const float* __restrict__ in,
                                                    float* __restrict__ out,
                                                    const float* __restrict__ sigmas,
                                                    const int* __restrict__ steps,
                                                    const int* __restrict__ q,
                                                    const _Float16* __restrict__ Wg) {
    __shared__ alignas(16) _Float16 YL[RB * WDIM];    // 32KB: Y[i][c] swizzled

    int b, r0, s, rad;
    if constexpr (QUEUED) {
        int d = q[QOFF + blockIdx.x];
        b   = d & 511;
        r0  = ((d >> 9) & 3) << 6;
        s   = (d >> 11) & 31;
        rad = (d >> 16) & 127;
    } else {
        int bid = blockIdx.x;
        int e = (bid & 7) * (NBAND / 8) + (bid >> 3);
        b = e >> 2; r0 = (e & 3) * RB;
        s = steps[b];
        rad = (int)floorf(4.0f * sigmas[s] + 0.5f);
    }
    const _Float16* Wm = Wg + ((size_t)s << 16);
    const float*    Xb = in + ((size_t)b << 16);

    int ln = threadIdx.x & 63, wv = threadIdx.x >> 6;
    int lm = ln & 15, lq = ln >> 4;

    // ---------------- Phase V: Y[i][c] = sum_r W[r0+i][r] X[r][c] ----------------
    f32x4 acc[4][4];
    #pragma unroll
    for (int mt = 0; mt < 4; ++mt)
        #pragma unroll
        for (int nt = 0; nt < 4; ++nt) acc[mt][nt] = (f32x4)0.0f;

    int kt0 = max(0, r0 - rad) >> 5;
    int kt1 = min(WDIM - 1, r0 + RB - 1 + rad) >> 5;

    float xvc[4][8], xvn[4][8];

    auto xload = [&](int kt, float (&dst)[4][8]) {
        const float* xp = Xb + (size_t)((kt << 5) + lq * 8) * WDIM + wv * 64 + lm;
        #pragma unroll
        for (int nt = 0; nt < 4; ++nt)
            #pragma unroll
            for (int jj = 0; jj < 8; ++jj)
                dst[nt][jj] = xp[(size_t)jj * WDIM + nt * 16];
    };
    auto vtile = [&](int kt, float (&xv)[4][8]) {
        f16x8 af[4];
        #pragma unroll
        for (int mt = 0; mt < 4; ++mt)
            af[mt] = *(const f16x8*)(Wm + (size_t)(r0 + mt * 16 + lm) * WDIM + (kt << 5) + lq * 8);
        #pragma unroll
        for (int nt = 0; nt < 4; ++nt) {
            f16x8 bf;
            #pragma unroll
            for (int jj = 0; jj < 8; ++jj) bf[jj] = (_Float16)xv[nt][jj];
            #pragma unroll
            for (int mt = 0; mt < 4; ++mt)
                acc[mt][nt] = __builtin_amdgcn_mfma_f32_16x16x32_f16(af[mt], bf, acc[mt][nt], 0, 0, 0);
        }
    };

    xload(kt0, xvc);                       // prologue
    for (int kt = kt0; kt <= kt1; ++kt) {
        if (kt < kt1) xload(kt + 1, xvn);  // issue next tile BEFORE consuming cur
        vtile(kt, xvc);                    // cvt+mfma cover xvn's latency
        if (kt < kt1) {
            #pragma unroll
            for (int nt = 0; nt < 4; ++nt)
                #pragma unroll
                for (int jj = 0; jj < 8; ++jj) xvc[nt][jj] = xvn[nt][jj];
        }
    }

    // write Y to swizzled LDS: D layout row=(lq*4+g), col=lm per 16x16 tile
    #pragma unroll
    for (int mt = 0; mt < 4; ++mt)
        #pragma unroll
        for (int nt = 0; nt < 4; ++nt)
            #pragma unroll
            for (int g = 0; g < 4; ++g) {
                int i = mt * 16 + lq * 4 + g;
                int c = wv * 64 + nt * 16 + lm;
                YL[(i << 8) + (c ^ ((i & 7) << 3))] = (_Float16)acc[mt][nt][g];
            }

    // ---------------- Phase H: Z[i][j] = sum_c Y[i][c] W[j][c] ----------------
    int jlo = wv * 64;
    int hk0 = max(0, jlo - rad) >> 5;
    int hk1 = min(WDIM - 1, jlo + 63 + rad) >> 5;

    f16x8 bfc[4], bfn[4];
    auto wload = [&](int kt, f16x8 (&bf)[4]) {
        #pragma unroll
        for (int nt = 0; nt < 4; ++nt)
            bf[nt] = *(const f16x8*)(Wm + (size_t)(jlo + nt * 16 + lm) * WDIM + (kt << 5) + lq * 8);
    };
    wload(hk0, bfc);                       // issued BEFORE the barrier (global-only)
    __syncthreads();

    f32x4 hac[4][4];
    #pragma unroll
    for (int mt = 0; mt < 4; ++mt)
        #pragma unroll
        for (int nt = 0; nt < 4; ++nt) hac[mt][nt] = (f32x4)0.0f;

    for (int kt = hk0; kt <= hk1; ++kt) {
        if (kt < hk1) wload(kt + 1, bfn);
        f16x8 af[4];
        #pragma unroll
        for (int mt = 0; mt < 4; ++mt) {
            int i = mt * 16 + lm;
            int c0 = (kt << 5) + lq * 8;
            af[mt] = *(const f16x8*)&YL[(i << 8) + (c0 ^ ((i & 7) << 3))];
        }
        #pragma unroll
        for (int mt = 0; mt < 4; ++mt)
            #pragma unroll
            for (int nt = 0; nt < 4; ++nt)
                hac[mt][nt] = __builtin_amdgcn_mfma_f32_16x16x32_f16(af[mt], bfc[nt], hac[mt][nt], 0, 0, 0);
        if (kt < hk1) {
            #pragma unroll
            for (int nt = 0; nt < 4; ++nt) bfc[nt] = bfn[nt];
        }
    }

    float* ob = out + ((size_t)b << 16);
    #pragma unroll
    for (int mt = 0; mt < 4; ++mt)
        #pragma unroll
        for (int nt = 0; nt < 4; ++nt)
            #pragma unroll
            for (int g = 0; g < 4; ++g)
                ob[(size_t)(r0 + mt * 16 + lq * 4 + g) * WDIM + jlo + nt * 16 + lm] = hac[mt][nt][g];
}

// ---------- fallback path (only if ws too small; needs no workspace) ----------
__device__ __forceinline__ int make_weights161(int b, const float* __restrict__ sigmas,
                                               const int* __restrict__ steps,
                                               float* wl, float* red) {
    int t = threadIdx.x;
    float sigma = sigmas[steps[b]];
    float radf = floorf(4.0f * sigma + 0.5f);
    if (t < 192) {
        float w = 0.0f;
        if (t < 161) {
            float off = (float)(t - 80);
            if (fabsf(off) <= radf) { float z = off / sigma; w = expf(-0.5f * z * z); }
        }
        wl[t] = w;
    }
    __syncthreads();
    if (t < 64) {
        float v = wl[t] + wl[t + 64] + wl[t + 128];
        #pragma unroll
        for (int o = 32; o > 0; o >>= 1) v += __shfl_down(v, o);
        if (t == 0) red[0] = 1.0f / v;
    }
    __syncthreads();
    float rs = red[0];
    if (t < 161) wl[t] *= rs;
    __syncthreads();
    return (int)radf;
}

__global__ __launch_bounds__(256) void vblur_nt(const float* __restrict__ in,
                                                float* __restrict__ out,
                                                const float* __restrict__ sigmas,
                                                const int* __restrict__ steps) {
    __shared__ float wl[192];
    __shared__ float red[1];
    int bid = blockIdx.x;
    int b = bid >> 4, i0 = (bid & 15) * 16;
    int rad = make_weights161(b, sigmas, steps, wl, red);
    int j = threadIdx.x;
    const float* inb = in + (size_t)b * WDIM * WDIM;
    float acc[16];
    #pragma unroll
    for (int ii = 0; ii < 16; ++ii) acc[ii] = 0.0f;
    for (int u = -rad; u <= rad; ++u) {
        float w = wl[80 + u];
        #pragma unroll
        for (int ii = 0; ii < 16; ++ii)
            acc[ii] = fmaf(w, inb[reflect(i0 + ii + u) * WDIM + j], acc[ii]);
    }
    #pragma unroll
    for (int ii = 0; ii < 16; ++ii)
        out[((size_t)b * WDIM + (i0 + ii)) * WDIM + j] = acc[ii];
}

__global__ __launch_bounds__(256) void hblur_inplace(float* __restrict__ buf,
                                                     const float* __restrict__ sigmas,
                                                     const int* __restrict__ steps) {
    __shared__ float wl[192];
    __shared__ float red[1];
    __shared__ float rp[WDIM + 160];
    int bid = blockIdx.x;
    int b = bid >> 8, i = bid & 255;
    float* row = buf + ((size_t)b * WDIM + i) * WDIM;
    int t = threadIdx.x;
    for (int s = t; s < WDIM + 160; s += 256) rp[s] = row[reflect(s - 80)];
    int rad = make_weights161(b, sigmas, steps, wl, red);
    float acc = 0.0f;
    for (int u = -rad; u <= rad; ++u) acc = fmaf(wl[80 + u], rp[80 + t + u], acc);
    row[t] = acc;
}
// --------------------------------------------------------------------------------

extern "C" void kernel_launch(void* const* d_in, const int* in_sizes, int n_in,
                              void* d_out, int out_size, void* d_ws, size_t ws_size,
                              hipStream_t stream) {
    const float* x     = (const float*)d_in[0];
    const float* sig   = (const float*)d_in[1];
    const int*   steps = (const int*)d_in[2];
    float* out = (float*)d_out;

    const size_t need = (size_t)WOFF + (size_t)NSIG * WDIM * WDIM * 2;
    if (ws_size >= need) {
        int* q = (int*)d_ws;
        _Float16* Wg = (_Float16*)((char*)d_ws + WOFF);
        build_w<<<dim3(NSIG, 8), 256, 0, stream>>>(sig, Wg);
        build_queue<<<1, 256, 0, stream>>>(sig, steps, q);
        blur_mfma<true><<<NBAND, 256, 0, stream>>>(x, out, sig, steps, q, Wg);
    } else {
        vblur_nt<<<NSAMP * 16, 256, 0, stream>>>(x, out, sig, steps);
        hblur_inplace<<<NSAMP * WDIM, 256, 0, stream>>>(out, sig, steps);
    }
}

// Round 16
// 84.702 us; speedup vs baseline: 1.0046x; 1.0046x over previous
//
#include <hip/hip_runtime.h>

#define WDIM  256
#define NSAMP 512
#define NSIG  32
#define RB    64                 // band rows per block-task
#define NBAND 2048
#define QOFF  16                 // ints; queue table q[QOFF..]
#define WOFF  65536              // byte offset of W matrices inside d_ws

typedef float    f32x4 __attribute__((ext_vector_type(4)));
typedef _Float16 f16x8 __attribute__((ext_vector_type(8)));

__device__ __forceinline__ int reflect(int q) {
    q = (q < 0) ? (-q - 1) : q;
    return (q >= WDIM) ? (2 * WDIM - 1 - q) : q;
}

// ---- kernel 1: build 32 reflect-folded banded weight matrices (f16) ----
// W_s[i][r] = wz(r-i) + wz(-r-1-i) + wz(511-r-i), wz = masked+normalized gaussian.
__global__ __launch_bounds__(256) void build_w(const float* __restrict__ sigmas,
                                               _Float16* __restrict__ Wg) {
    __shared__ float wl[161];
    __shared__ float red;
    int s = blockIdx.x, t = threadIdx.x;
    float sigma = sigmas[s];
    float radf = floorf(4.0f * sigma + 0.5f);
    if (t < 161) {
        float off = (float)(t - 80);
        float w = 0.0f;
        if (fabsf(off) <= radf) { float z = off / sigma; w = expf(-0.5f * z * z); }
        wl[t] = w;
    }
    __syncthreads();
    if (t < 64) {
        float v = wl[t] + wl[t + 64] + (t < 33 ? wl[t + 128] : 0.0f);
        #pragma unroll
        for (int o = 32; o > 0; o >>= 1) v += __shfl_down(v, o);
        if (t == 0) red = 1.0f / v;
    }
    __syncthreads();
    float rs = red;
    int i = t;
    _Float16* wrow = Wg + ((size_t)s << 16) + (i << 8);
    for (int rq = blockIdx.y * 4; rq < blockIdx.y * 4 + 4; ++rq) {
        f16x8 v;
        #pragma unroll
        for (int j = 0; j < 8; ++j) {
            int r = rq * 8 + j;
            int d1 = r - i, d2 = -r - 1 - i, d3 = 511 - r - i;
            float w = 0.0f;
            if (d1 >= -80 && d1 <= 80) w += wl[d1 + 80];
            if (d2 >= -80)             w += wl[d2 + 80];
            if (d3 <= 80)              w += wl[d3 + 80];
            v[j] = (_Float16)(w * rs);
        }
        *(f16x8*)(wrow + rq * 8) = v;
    }
}

// ---- kernel 2: striped-LPT queue with PACKED descriptors ----
// desc = b | band<<9 | step<<11 | rad<<16  (one load decodes everything)
__global__ void build_queue(const float* __restrict__ sigmas,
                            const int* __restrict__ steps,
                            int* __restrict__ q) {
    __shared__ int hist[32];
    __shared__ int base[32];
    int t = threadIdx.x;
    if (t < 32) hist[t] = 0;
    __syncthreads();
    int nb2[2], rd2[2], st2[2];
    #pragma unroll
    for (int k = 0; k < 2; ++k) {
        int samp = t + 256 * k;
        int st = steps[samp];
        float sigma = sigmas[st];
        int rad = (int)floorf(4.0f * sigma + 0.5f);
        st2[k] = st; rd2[k] = rad;
        nb2[k] = (2 * rad + 15) >> 3;
        atomicAdd(&hist[nb2[k]], 1);
    }
    __syncthreads();
    if (t == 0) {
        int acc = 0;
        for (int bin = 31; bin >= 0; --bin) { base[bin] = acc; acc += hist[bin]; }
    }
    __syncthreads();
    #pragma unroll
    for (int k = 0; k < 2; ++k) {
        int samp = t + 256 * k;
        int r = atomicAdd(&base[nb2[k]], 1);
        int x = r & 7;
        int p = r >> 3;
        #pragma unroll
        for (int jb = 0; jb < 4; ++jb)
            q[QOFF + (((p << 2) + jb) << 3) + x] =
                samp | (jb << 9) | (st2[k] << 11) | (rd2[k] << 16);
    }
}

// ---- kernel 3: fused MFMA blur, software-pipelined. ----
// Phase V: Y = W_band X; A=W rows direct; B=X column-slices via direct dword
//          loads, PIPELINED one K-tile ahead. Y -> swizzled LDS f16.
// Phase H: Z = Y W^T; A=Y from LDS; B=W rows direct, pipelined. f32 out.
template <bool QUEUED>
__global__ __launch_bounds__(256, 2) void blur_mfma(const float* __restrict__ in,
                                                    float* __restrict__ out,
                                                    const float* __restrict__ sigmas,
                                                    const int* __restrict__ steps,
                                                    const int* __restrict__ q,
                                                    const _Float16* __restrict__ Wg) {
    __shared__ alignas(16) _Float16 YL[RB * WDIM];    // 32KB: Y[i][c] swizzled

    int b, r0, s, rad;
    if constexpr (QUEUED) {
        int d = q[QOFF + blockIdx.x];
        b   = d & 511;
        r0  = ((d >> 9) & 3) << 6;
        s   = (d >> 11) & 31;
        rad = (d >> 16) & 127;
    } else {
        int bid = blockIdx.x;
        int e = (bid & 7) * (NBAND / 8) + (bid >> 3);
        b = e >> 2; r0 = (e & 3) * RB;
        s = steps[b];
        rad = (int)floorf(4.0f * sigmas[s] + 0.5f);
    }
    const _Float16* Wm = Wg + ((size_t)s << 16);
    const float*    Xb = in + ((size_t)b << 16);

    int ln = threadIdx.x & 63, wv = threadIdx.x >> 6;
    int lm = ln & 15, lq = ln >> 4;

    // ---------------- Phase V: Y[i][c] = sum_r W[r0+i][r] X[r][c] ----------------
    f32x4 acc[4][4];
    #pragma unroll
    for (int mt = 0; mt < 4; ++mt)
        #pragma unroll
        for (int nt = 0; nt < 4; ++nt) acc[mt][nt] = (f32x4)0.0f;

    int kt0 = max(0, r0 - rad) >> 5;
    int kt1 = min(WDIM - 1, r0 + RB - 1 + rad) >> 5;

    float xvc[4][8], xvn[4][8];

    auto xload = [&](int kt, float (&dst)[4][8]) {
        const float* xp = Xb + (size_t)((kt << 5) + lq * 8) * WDIM + wv * 64 + lm;
        #pragma unroll
        for (int nt = 0; nt < 4; ++nt)
            #pragma unroll
            for (int jj = 0; jj < 8; ++jj)
                dst[nt][jj] = xp[(size_t)jj * WDIM + nt * 16];
    };
    auto vtile = [&](int kt, float (&xv)[4][8]) {
        f16x8 af[4];
        #pragma unroll
        for (int mt = 0; mt < 4; ++mt)
            af[mt] = *(const f16x8*)(Wm + (size_t)(r0 + mt * 16 + lm) * WDIM + (kt << 5) + lq * 8);
        #pragma unroll
        for (int nt = 0; nt < 4; ++nt) {
            f16x8 bf;
            #pragma unroll
            for (int jj = 0; jj < 8; ++jj) bf[jj] = (_Float16)xv[nt][jj];
            #pragma unroll
            for (int mt = 0; mt < 4; ++mt)
                acc[mt][nt] = __builtin_amdgcn_mfma_f32_16x16x32_f16(af[mt], bf, acc[mt][nt], 0, 0, 0);
        }
    };

    xload(kt0, xvc);                       // prologue
    for (int kt = kt0; kt <= kt1; ++kt) {
        if (kt < kt1) xload(kt + 1, xvn);  // issue next tile BEFORE consuming cur
        vtile(kt, xvc);                    // cvt+mfma cover xvn's latency
        if (kt < kt1) {
            #pragma unroll
            for (int nt = 0; nt < 4; ++nt)
                #pragma unroll
                for (int jj = 0; jj < 8; ++jj) xvc[nt][jj] = xvn[nt][jj];
        }
    }

    // write Y to swizzled LDS: D layout row=(lq*4+g), col=lm per 16x16 tile
    #pragma unroll
    for (int mt = 0; mt < 4; ++mt)
        #pragma unroll
        for (int nt = 0; nt < 4; ++nt)
            #pragma unroll
            for (int g = 0; g < 4; ++g) {
                int i = mt * 16 + lq * 4 + g;
                int c = wv * 64 + nt * 16 + lm;
                YL[(i << 8) + (c ^ ((i & 7) << 3))] = (_Float16)acc[mt][nt][g];
            }

    // ---------------- Phase H: Z[i][j] = sum_c Y[i][c] W[j][c] ----------------
    int jlo = wv * 64;
    int hk0 = max(0, jlo - rad) >> 5;
    int hk1 = min(WDIM - 1, jlo + 63 + rad) >> 5;

    f16x8 bfc[4], bfn[4];
    auto wload = [&](int kt, f16x8 (&bf)[4]) {
        #pragma unroll
        for (int nt = 0; nt < 4; ++nt)
            bf[nt] = *(const f16x8*)(Wm + (size_t)(jlo + nt * 16 + lm) * WDIM + (kt << 5) + lq * 8);
    };
    wload(hk0, bfc);                       // issued BEFORE the barrier (global-only)
    __syncthreads();

    f32x4 hac[4][4];
    #pragma unroll
    for (int mt = 0; mt < 4; ++mt)
        #pragma unroll
        for (int nt = 0; nt < 4; ++nt) hac[mt][nt] = (f32x4)0.0f;

    for (int kt = hk0; kt <= hk1; ++kt) {
        if (kt < hk1) wload(kt + 1, bfn);
        f16x8 af[4];
        #pragma unroll
        for (int mt = 0; mt < 4; ++mt) {
            int i = mt * 16 + lm;
            int c0 = (kt << 5) + lq * 8;
            af[mt] = *(const f16x8*)&YL[(i << 8) + (c0 ^ ((i & 7) << 3))];
        }
        #pragma unroll
        for (int mt = 0; mt < 4; ++mt)
            #pragma unroll
            for (int nt = 0; nt < 4; ++nt)
                hac[mt][nt] = __builtin_amdgcn_mfma_f32_16x16x32_f16(af[mt], bfc[nt], hac[mt][nt], 0, 0, 0);
        if (kt < hk1) {
            #pragma unroll
            for (int nt = 0; nt < 4; ++nt) bfc[nt] = bfn[nt];
        }
    }

    float* ob = out + ((size_t)b << 16);
    #pragma unroll
    for (int mt = 0; mt < 4; ++mt)
        #pragma unroll
        for (int nt = 0; nt < 4; ++nt)
            #pragma unroll
            for (int g = 0; g < 4; ++g)
                ob[(size_t)(r0 + mt * 16 + lq * 4 + g) * WDIM + jlo + nt * 16 + lm] = hac[mt][nt][g];
}

// ---------- fallback path (only if ws too small; needs no workspace) ----------
__device__ __forceinline__ int make_weights161(int b, const float* __restrict__ sigmas,
                                               const int* __restrict__ steps,
                                               float* wl, float* red) {
    int t = threadIdx.x;
    float sigma = sigmas[steps[b]];
    float radf = floorf(4.0f * sigma + 0.5f);
    if (t < 192) {
        float w = 0.0f;
        if (t < 161) {
            float off = (float)(t - 80);
            if (fabsf(off) <= radf) { float z = off / sigma; w = expf(-0.5f * z * z); }
        }
        wl[t] = w;
    }
    __syncthreads();
    if (t < 64) {
        float v = wl[t] + wl[t + 64] + wl[t + 128];
        #pragma unroll
        for (int o = 32; o > 0; o >>= 1) v += __shfl_down(v, o);
        if (t == 0) red[0] = 1.0f / v;
    }
    __syncthreads();
    float rs = red[0];
    if (t < 161) wl[t] *= rs;
    __syncthreads();
    return (int)radf;
}

__global__ __launch_bounds__(256) void vblur_nt(const float* __restrict__ in,
                                                float* __restrict__ out,
                                                const float* __restrict__ sigmas,
                                                const int* __restrict__ steps) {
    __shared__ float wl[192];
    __shared__ float red[1];
    int bid = blockIdx.x;
    int b = bid >> 4, i0 = (bid & 15) * 16;
    int rad = make_weights161(b, sigmas, steps, wl, red);
    int j = threadIdx.x;
    const float* inb = in + (size_t)b * WDIM * WDIM;
    float acc[16];
    #pragma unroll
    for (int ii = 0; ii < 16; ++ii) acc[ii] = 0.0f;
    for (int u = -rad; u <= rad; ++u) {
        float w = wl[80 + u];
        #pragma unroll
        for (int ii = 0; ii < 16; ++ii)
            acc[ii] = fmaf(w, inb[reflect(i0 + ii + u) * WDIM + j], acc[ii]);
    }
    #pragma unroll
    for (int ii = 0; ii < 16; ++ii)
        out[((size_t)b * WDIM + (i0 + ii)) * WDIM + j] = acc[ii];
}

__global__ __launch_bounds__(256) void hblur_inplace(float* __restrict__ buf,
                                                     const float* __restrict__ sigmas,
                                                     const int* __restrict__ steps) {
    __shared__ float wl[192];
    __shared__ float red[1];
    __shared__ float rp[WDIM + 160];
    int bid = blockIdx.x;
    int b = bid >> 8, i = bid & 255;
    float* row = buf + ((size_t)b * WDIM + i) * WDIM;
    int t = threadIdx.x;
    for (int s = t; s < WDIM + 160; s += 256) rp[s] = row[reflect(s - 80)];
    int rad = make_weights161(b, sigmas, steps, wl, red);
    float acc = 0.0f;
    for (int u = -rad; u <= rad; ++u) acc = fmaf(wl[80 + u], rp[80 + t + u], acc);
    row[t] = acc;
}
// --------------------------------------------------------------------------------

extern "C" void kernel_launch(void* const* d_in, const int* in_sizes, int n_in,
                              void* d_out, int out_size, void* d_ws, size_t ws_size,
                              hipStream_t stream) {
    const float* x     = (const float*)d_in[0];
    const float* sig   = (const float*)d_in[1];
    const int*   steps = (const int*)d_in[2];
    float* out = (float*)d_out;

    const size_t need = (size_t)WOFF + (size_t)NSIG * WDIM * WDIM * 2;
    if (ws_size >= need) {
        int* q = (int*)d_ws;
        _Float16* Wg = (_Float16*)((char*)d_ws + WOFF);
        build_w<<<dim3(NSIG, 8), 256, 0, stream>>>(sig, Wg);
        build_queue<<<1, 256, 0, stream>>>(sig, steps, q);
        blur_mfma<true><<<NBAND, 256, 0, stream>>>(x, out, sig, steps, q, Wg);
    } else {
        vblur_nt<<<NSAMP * 16, 256, 0, stream>>>(x, out, sig, steps);
        hblur_inplace<<<NSAMP * WDIM, 256, 0, stream>>>(out, sig, steps);
    }
}